// Round 10
// baseline (5718.337 us; speedup 1.0000x reference)
//
#include <hip/hip_runtime.h>
#include <hip/hip_bf16.h>

// ---------------------------------------------------------------------------
// CharRNN: emb -> 4x conv1d(SAME) -> concat -> GRU(256) last state.
//
// xw[b,t,:] = sum_{d=0..4} EmbW[d][X[b,t+d-2]][:]  (beff folded into d=2)
//
// R10: R9 counters showed the cross-XCD h-exchange IS the kernel (FETCH 136MB,
// 96GB/s HBM, MfmaUtil 0.94%): agent atomics bypass caches -> ~3-4k cyc/step
// of serialized HBM latency. Eliminate ALL cross-block comms: 8 blocks x 1024
// threads (16 waves); block = 16 batch rows x all 768 cols. Wh fits in the
// CU's aggregate register file: 96 VGPR/lane (under the 128 budget), M=16
// all-real (no replicated-A waste). h in LDS only (hi/lo bf16, parity dbuf,
// XOR bank swizzle), 2 barriers/step. Biases folded into MFMA acc init;
// xw double-buffered in LDS as bf16.
// ---------------------------------------------------------------------------

typedef float f32x4 __attribute__((ext_vector_type(4)));
typedef short s16x8 __attribute__((ext_vector_type(8)));
typedef unsigned short u16;
typedef unsigned short u16x4 __attribute__((ext_vector_type(4)));
typedef unsigned int   u32;

// ws byte offsets
#define OFF_WC    0u         // f32  [5][64][768]
#define OFF_EMBW  983040u    // f32  [5][128][768]
#define OFF_BEFF  2949120u   // f32  [768]
#define OFF_WHP   2952192u   // bf16 [768][256] (Wh^T)
#define OFF_MODE  3345408u   // int
#define WS_NEED   3345472u

__device__ __forceinline__ float bf2f(u16 v){
  unsigned u = ((unsigned)v) << 16; return __builtin_bit_cast(float, u);
}
__device__ __forceinline__ u16 f2bf(float f){
  unsigned u = __builtin_bit_cast(unsigned, f);
  unsigned r = u + 0x7FFFu + ((u >> 16) & 1u);
  return (u16)(r >> 16);
}
__device__ __forceinline__ float ldv(const void* p, int i, int m){
  return m ? ((const float*)p)[i] : bf2f(((const u16*)p)[i]);
}

// ---- probe: detect storage dtype of emb_table ----
__global__ void k_probe(const void* __restrict__ emb, char* ws){
  const u16* w = (const u16*)emb;
  const int ln = threadIdx.x;
  bool bad = false;
  for (int j = 0; j < 8; ++j){
    u16 v = w[ln*8 + j];
    if (((v >> 7) & 0xFF) >= 0x86) bad = true;
  }
  unsigned long long m = __ballot(bad);
  if (ln == 0) *(int*)(ws + OFF_MODE) = (__popcll(m) > 4) ? 1 : 0;
}

// ---- Wc[d][e][j] = sum_br sum_c w_br[d-2+pad][e][c] * Wx[off_br+c][j] ----
__global__ void k_wc(const void* __restrict__ w2, const void* __restrict__ w3,
                     const void* __restrict__ w4, const void* __restrict__ w5,
                     const void* __restrict__ Wx, char* ws){
  const int md = *(const int*)(ws + OFF_MODE);
  const int d = blockIdx.x >> 6;
  const int e = blockIdx.x & 63;
  const int j0 = threadIdx.x;
  const void* wv[4] = {w2,w3,w4,w5};
  const int Kk[4] = {2,3,4,5}, pd[4] = {0,1,1,2};
  float a0=0.f, a1=0.f, a2=0.f;
  for (int br=0; br<4; ++br){
    int k = d - 2 + pd[br];
    if (k < 0 || k >= Kk[br]) continue;
    const int wbase  = (k*64 + e)*128;
    const int wxbase = (br*128)*768;
    for (int c=0; c<128; ++c){
      float wcv = ldv(wv[br], wbase + c, md);
      a0 += wcv * ldv(Wx, wxbase + c*768 + j0      , md);
      a1 += wcv * ldv(Wx, wxbase + c*768 + j0 + 256, md);
      a2 += wcv * ldv(Wx, wxbase + c*768 + j0 + 512, md);
    }
  }
  float* o = (float*)(ws + OFF_WC) + (d*64 + e)*768;
  o[j0] = a0; o[j0+256] = a1; o[j0+512] = a2;
}

// ---- beff[j] = b_in[j] + sum_br sum_c b_br[c]*Wx[off+c][j] ----
__global__ void k_beff(const void* __restrict__ b2, const void* __restrict__ b3,
                       const void* __restrict__ b4, const void* __restrict__ b5,
                       const void* __restrict__ Wx, const void* __restrict__ bin,
                       char* ws){
  const int md = *(const int*)(ws + OFF_MODE);
  int j = blockIdx.x*256 + threadIdx.x;
  if (j >= 768) return;
  const void* bv[4] = {b2,b3,b4,b5};
  float acc = ldv(bin, j, md);
  for (int br=0; br<4; ++br)
    for (int c=0; c<128; ++c)
      acc += ldv(bv[br], c, md) * ldv(Wx, (br*128 + c)*768 + j, md);
  ((float*)(ws + OFF_BEFF))[j] = acc;
}

// ---- EmbW[d][ch][j] = sum_e emb[ch][e]*Wc[d][e][j]  (+beff when d==2) ----
__global__ void k_embw(const void* __restrict__ emb, char* ws){
  const int md = *(const int*)(ws + OFF_MODE);
  const int d = blockIdx.x >> 7, ch = blockIdx.x & 127;
  const float* wc = (const float*)(ws + OFF_WC) + d*64*768;
  const float* be = (const float*)(ws + OFF_BEFF);
  float* ew = (float*)(ws + OFF_EMBW) + (size_t)(d*128 + ch)*768;
  const int j0 = threadIdx.x;
  float a0=0.f, a1=0.f, a2=0.f;
  for (int e=0; e<64; ++e){
    float ev = ldv(emb, ch*64 + e, md);
    a0 += ev*wc[e*768 + j0      ];
    a1 += ev*wc[e*768 + j0 + 256];
    a2 += ev*wc[e*768 + j0 + 512];
  }
  if (d == 2){ a0 += be[j0]; a1 += be[j0+256]; a2 += be[j0+512]; }
  ew[j0] = a0; ew[j0+256] = a1; ew[j0+512] = a2;
}

// ---- whp[j][k] = Wh[k][j]  (bf16 out) ----
__global__ void k_whp(const void* __restrict__ Wh, char* ws){
  const int md = *(const int*)(ws + OFF_MODE);
  const int j = blockIdx.x, k = threadIdx.x;
  ((u16*)(ws + OFF_WHP))[j*256 + k] = f2bf(ldv(Wh, k*768 + j, md));
}

// ---- GRU: 8 blocks (16 batch rows each) x 1024 threads (16 waves) ----
__launch_bounds__(1024, 1)
__global__ void k_gru(const int* __restrict__ X, const void* __restrict__ brec,
                      const char* __restrict__ ws, void* __restrict__ outv){
  const int tid = threadIdx.x;
  const int w   = tid >> 6, ln = tid & 63;
  const int l15 = ln & 15, l4 = ln >> 4;
  const int g = blockIdx.x;

  const int md = *(const int*)(ws + OFF_MODE);
  const float* embw = (const float*)(ws + OFF_EMBW);
  const u16*   whp  = (const u16*)(ws + OFF_WHP);

  __shared__ u16   hbuf[4*16*272];   // [par*2+hl][row][272], XOR-swz  (34.8KB)
  __shared__ u16   xwb[2*16*776];    // [buf][row][768+pad] bf16       (49.7KB)
  __shared__ float hwlds[16*772];    // [row][768+pad] f32             (49.4KB)

  // persistent Wh B-frags: wave w owns col w*16+l15 of each gate
  s16x8 Bf[3][8];
  #pragma unroll
  for (int gg=0; gg<3; ++gg){
    const int col = gg*256 + w*16 + l15;
    #pragma unroll
    for (int q=0; q<8; ++q)
      Bf[gg][q] = *(const s16x8*)(whp + col*256 + q*32 + l4*8);
  }
  // recurrent biases folded into acc init (col-dependent only)
  const float bz = ldv(brec,       w*16 + l15, md);
  const float br_ = ldv(brec, 256 + w*16 + l15, md);
  const float bh = ldv(brec, 512 + w*16 + l15, md);

  // gates assignment: thread -> row ur, 4 h-cols uc0..+3
  const int ur = tid >> 6, uc0 = (tid & 63) * 4;

  // zero h planes (both parities)
  for (int i = tid; i < 8704; i += 1024) ((u32*)hbuf)[i] = 0u;

  // prologue: xw(0) -> xwb buf0
  #pragma unroll
  for (int k2=0; k2<3; ++k2){
    const int c = tid + k2*1024;
    const int row = c/192, cc = c - row*192;
    f32x4 n = {0.f,0.f,0.f,0.f};
    #pragma unroll
    for (int d=0; d<5; ++d){
      const int tok = d - 2;
      if ((unsigned)tok < 512u){
        const int ch = X[(g*16+row)*512 + tok] & 127;
        n += *(const f32x4*)(embw + (size_t)(d*128+ch)*768 + cc*4);
      }
    }
    u16x4 o; o[0]=f2bf(n.x); o[1]=f2bf(n.y); o[2]=f2bf(n.z); o[3]=f2bf(n.w);
    *(u16x4*)&xwb[(0*16 + row)*776 + cc*4] = o;
  }
  float hprev[4] = {0.f,0.f,0.f,0.f};
  __syncthreads();

  for (int s = 0; s < 512; ++s){
    const int par = s & 1;

    // A) gather xw(s+1) -> xwb[par^1]  (VMEM latency overlaps MFMA via TLP)
    if (s < 511){
      #pragma unroll
      for (int k2=0; k2<3; ++k2){
        const int c = tid + k2*1024;
        const int row = c/192, cc = c - row*192;
        f32x4 n = {0.f,0.f,0.f,0.f};
        #pragma unroll
        for (int d=0; d<5; ++d){
          const int tok = s + 1 + d - 2;
          if ((unsigned)tok < 512u){
            const int ch = X[(g*16+row)*512 + tok] & 127;
            n += *(const f32x4*)(embw + (size_t)(d*128+ch)*768 + cc*4);
          }
        }
        u16x4 o; o[0]=f2bf(n.x); o[1]=f2bf(n.y); o[2]=f2bf(n.z); o[3]=f2bf(n.w);
        *(u16x4*)&xwb[((par^1)*16 + row)*776 + cc*4] = o;
      }
    }

    // B) hw = (h_hi + h_lo) @ Wh + brec : 48 MFMAs/wave, acc init = bias
    f32x4 a0 = {bz,bz,bz,bz}, a1 = {br_,br_,br_,br_}, a2 = {bh,bh,bh,bh};
    #pragma unroll
    for (int q=0; q<8; ++q){
      const int colk = (q*32 + l4*8) ^ ((l15 & 7) << 3);
      const s16x8 ahi = *(const s16x8*)&hbuf[((par*2+0)*16 + l15)*272 + colk];
      const s16x8 alo = *(const s16x8*)&hbuf[((par*2+1)*16 + l15)*272 + colk];
      a0 = __builtin_amdgcn_mfma_f32_16x16x32_bf16(ahi, Bf[0][q], a0, 0,0,0);
      a1 = __builtin_amdgcn_mfma_f32_16x16x32_bf16(ahi, Bf[1][q], a1, 0,0,0);
      a2 = __builtin_amdgcn_mfma_f32_16x16x32_bf16(ahi, Bf[2][q], a2, 0,0,0);
      a0 = __builtin_amdgcn_mfma_f32_16x16x32_bf16(alo, Bf[0][q], a0, 0,0,0);
      a1 = __builtin_amdgcn_mfma_f32_16x16x32_bf16(alo, Bf[1][q], a1, 0,0,0);
      a2 = __builtin_amdgcn_mfma_f32_16x16x32_bf16(alo, Bf[2][q], a2, 0,0,0);
    }
    // C) publish hw: D row = l4*4+p (all 16 real), col = w*16+l15
    #pragma unroll
    for (int p=0; p<4; ++p){
      const int rbase = (l4*4+p)*772 + w*16 + l15;
      hwlds[rbase      ] = a0[p];
      hwlds[rbase + 256] = a1[p];
      hwlds[rbase + 512] = a2[p];
    }
    __syncthreads();                          // bar0: hw ready

    // D) gates: unit (ur, uc0..+3)
    const f32x4 hz4 = *(const f32x4*)&hwlds[ur*772 +       uc0];
    const f32x4 hr4 = *(const f32x4*)&hwlds[ur*772 + 256 + uc0];
    const f32x4 hh4 = *(const f32x4*)&hwlds[ur*772 + 512 + uc0];
    const u16x4 xz4 = *(const u16x4*)&xwb[(par*16 + ur)*776 +       uc0];
    const u16x4 xr4 = *(const u16x4*)&xwb[(par*16 + ur)*776 + 256 + uc0];
    const u16x4 xh4 = *(const u16x4*)&xwb[(par*16 + ur)*776 + 512 + uc0];
    float hn[4];
    #pragma unroll
    for (int j=0; j<4; ++j){
      const float z   = 1.f/(1.f + __expf(-(bf2f(xz4[j]) + hz4[j])));
      const float r   = 1.f/(1.f + __expf(-(bf2f(xr4[j]) + hr4[j])));
      const float pre = bf2f(xh4[j]) + r*hh4[j];
      const float e2  = __expf(-2.f*fabsf(pre));
      const float th  = __builtin_copysignf((1.f - e2)/(1.f + e2), pre);
      hn[j] = z*hprev[j] + (1.f - z)*th;
      hprev[j] = hn[j];
    }

    // E) publish h (split-bf16 hi/lo, swizzled) or final output
    if (s == 511){
      const int i0 = (g*16 + ur)*256 + uc0;
      if (md){
        ((float*)outv)[i0+0]=hn[0]; ((float*)outv)[i0+1]=hn[1];
        ((float*)outv)[i0+2]=hn[2]; ((float*)outv)[i0+3]=hn[3];
      } else {
        u16x4 o; o[0]=f2bf(hn[0]); o[1]=f2bf(hn[1]); o[2]=f2bf(hn[2]); o[3]=f2bf(hn[3]);
        *(u16x4*)&((u16*)outv)[i0] = o;
      }
    } else {
      u16x4 h4, lo4;
      #pragma unroll
      for (int j=0; j<4; ++j){
        h4[j]  = f2bf(hn[j]);
        lo4[j] = f2bf(hn[j] - bf2f(h4[j]));
      }
      const int cidx = uc0 ^ ((ur & 7) << 3);
      *(u16x4*)&hbuf[(((par^1)*2+0)*16 + ur)*272 + cidx] = h4;
      *(u16x4*)&hbuf[(((par^1)*2+1)*16 + ur)*272 + cidx] = lo4;
    }
    __syncthreads();                          // bar1: h(s+1)/xw(s+1) ready
  }
}

extern "C" void kernel_launch(void* const* d_in, const int* in_sizes, int n_in,
                              void* d_out, int out_size, void* d_ws, size_t ws_size,
                              hipStream_t stream){
  const int* X = (const int*)d_in[0];
  char* ws = (char*)d_ws;
  if (ws_size < WS_NEED) return;

  k_probe<<<  1,  64, 0, stream>>>(d_in[1], ws);
  k_wc   <<<320, 256, 0, stream>>>(d_in[2], d_in[4], d_in[6], d_in[8], d_in[10], ws);
  k_beff <<<  3, 256, 0, stream>>>(d_in[3], d_in[5], d_in[7], d_in[9], d_in[10], d_in[12], ws);
  k_embw <<<640, 256, 0, stream>>>(d_in[1], ws);
  k_whp  <<<768, 256, 0, stream>>>(d_in[11], ws);
  k_gru  <<<  8, 1024, 0, stream>>>(X, d_in[13], ws, d_out);
}

// Round 11
// 2136.901 us; speedup vs baseline: 2.6760x; 2.6760x over previous
//
#include <hip/hip_runtime.h>
#include <hip/hip_bf16.h>

// ---------------------------------------------------------------------------
// CharRNN: emb -> 4x conv1d(SAME) -> concat -> GRU(256) last state.
//
// xw[b,t,:] = beff + sum_{d=0..4} EmbW[d][X[b,t+d-2]][:]   (f32 tables in ws)
//
// R11: R10 proved no-comm is impossible (Wh needs 98304 u32-regs; any block
// gets <=65536 under the allocator's 2-blocks/CU budget). So keep R9's
// no-spill exchange structure (32 blocks = 8 groups x 4 col-slices, Bf=48
// regs, VGPR 88) and attack the exchange chain: R9 serialized 3 L3 legs
// (store-drain -> flag-RMW -> load ~2.7k cyc). Replace flags with
// SELF-VALIDATING h-words: steal bit0 of the lo half of each split-bf16 pair
// (error ~2^-17 rel) to carry the step-mark ((step)>>1)&1; pack (hi<<16)|lo.
// Producers fire-and-forget stores; consumers spin-load the data itself and
// validate marks per u32 (u64 tearing harmless). 1 latency leg instead of 3;
// 2 barriers/step instead of 3. WAR safety: parity regions + induction
// (publishing h(s+1) implies all blocks are past step s-1).
// ---------------------------------------------------------------------------

typedef float f32x4 __attribute__((ext_vector_type(4)));
typedef short s16x8 __attribute__((ext_vector_type(8)));
typedef int   i32x4 __attribute__((ext_vector_type(4)));
typedef unsigned short u16;
typedef unsigned int   u32;
typedef unsigned long long u64;

// ws byte offsets
#define OFF_WC    0u         // f32  [5][64][768]
#define OFF_EMBW  983040u    // f32  [5][128][768]
#define OFF_BEFF  2949120u   // f32  [768]
#define OFF_WHP   2952192u   // bf16 [768][256] (Wh^T)
#define OFF_MODE  3345408u   // int
#define OFF_HGP   3345472u   // u32 [2][8][16][256]  (par, group, row, hcol)
#define WS_NEED   3607616u

__device__ __forceinline__ float bf2f(u16 v){
  unsigned u = ((unsigned)v) << 16; return __builtin_bit_cast(float, u);
}
__device__ __forceinline__ u16 f2bf(float f){
  unsigned u = __builtin_bit_cast(unsigned, f);
  unsigned r = u + 0x7FFFu + ((u >> 16) & 1u);
  return (u16)(r >> 16);
}
__device__ __forceinline__ float ldv(const void* p, int i, int m){
  return m ? ((const float*)p)[i] : bf2f(((const u16*)p)[i]);
}

// ---- init: zero both h parity planes (mark bits 0 -> steps 0,1 validate) ----
__global__ void k_init(char* ws){
  int idx = blockIdx.x*256 + threadIdx.x;
  u32* hg = (u32*)(ws + OFF_HGP);
  if (idx < 65536) hg[idx] = 0u;
}

// ---- probe: detect storage dtype of emb_table ----
__global__ void k_probe(const void* __restrict__ emb, char* ws){
  const u16* w = (const u16*)emb;
  const int ln = threadIdx.x;
  bool bad = false;
  for (int j = 0; j < 8; ++j){
    u16 v = w[ln*8 + j];
    if (((v >> 7) & 0xFF) >= 0x86) bad = true;
  }
  unsigned long long m = __ballot(bad);
  if (ln == 0) *(int*)(ws + OFF_MODE) = (__popcll(m) > 4) ? 1 : 0;
}

// ---- Wc[d][e][j] = sum_br sum_c w_br[d-2+pad][e][c] * Wx[off_br+c][j] ----
__global__ void k_wc(const void* __restrict__ w2, const void* __restrict__ w3,
                     const void* __restrict__ w4, const void* __restrict__ w5,
                     const void* __restrict__ Wx, char* ws){
  const int md = *(const int*)(ws + OFF_MODE);
  const int d = blockIdx.x >> 6;
  const int e = blockIdx.x & 63;
  const int j0 = threadIdx.x;
  const void* wv[4] = {w2,w3,w4,w5};
  const int Kk[4] = {2,3,4,5}, pd[4] = {0,1,1,2};
  float a0=0.f, a1=0.f, a2=0.f;
  for (int br=0; br<4; ++br){
    int k = d - 2 + pd[br];
    if (k < 0 || k >= Kk[br]) continue;
    const int wbase  = (k*64 + e)*128;
    const int wxbase = (br*128)*768;
    for (int c=0; c<128; ++c){
      float wcv = ldv(wv[br], wbase + c, md);
      a0 += wcv * ldv(Wx, wxbase + c*768 + j0      , md);
      a1 += wcv * ldv(Wx, wxbase + c*768 + j0 + 256, md);
      a2 += wcv * ldv(Wx, wxbase + c*768 + j0 + 512, md);
    }
  }
  float* o = (float*)(ws + OFF_WC) + (d*64 + e)*768;
  o[j0] = a0; o[j0+256] = a1; o[j0+512] = a2;
}

// ---- beff[j] = b_in[j] + sum_br sum_c b_br[c]*Wx[off+c][j] ----
__global__ void k_beff(const void* __restrict__ b2, const void* __restrict__ b3,
                       const void* __restrict__ b4, const void* __restrict__ b5,
                       const void* __restrict__ Wx, const void* __restrict__ bin,
                       char* ws){
  const int md = *(const int*)(ws + OFF_MODE);
  int j = blockIdx.x*256 + threadIdx.x;
  if (j >= 768) return;
  const void* bv[4] = {b2,b3,b4,b5};
  float acc = ldv(bin, j, md);
  for (int br=0; br<4; ++br)
    for (int c=0; c<128; ++c)
      acc += ldv(bv[br], c, md) * ldv(Wx, (br*128 + c)*768 + j, md);
  ((float*)(ws + OFF_BEFF))[j] = acc;
}

// ---- EmbW[d][ch][j] = sum_e emb[ch][e] * Wc[d][e][j]  (f32 out) ----
__global__ void k_embw(const void* __restrict__ emb, char* ws){
  const int md = *(const int*)(ws + OFF_MODE);
  const int d = blockIdx.x >> 7, ch = blockIdx.x & 127;
  const float* wc = (const float*)(ws + OFF_WC) + d*64*768;
  float* ew = (float*)(ws + OFF_EMBW) + (size_t)(d*128 + ch)*768;
  const int j0 = threadIdx.x;
  float a0=0.f, a1=0.f, a2=0.f;
  for (int e=0; e<64; ++e){
    float ev = ldv(emb, ch*64 + e, md);
    a0 += ev*wc[e*768 + j0      ];
    a1 += ev*wc[e*768 + j0 + 256];
    a2 += ev*wc[e*768 + j0 + 512];
  }
  ew[j0] = a0; ew[j0+256] = a1; ew[j0+512] = a2;
}

// ---- whp[j][k] = Wh[k][j]  (bf16 out) ----
__global__ void k_whp(const void* __restrict__ Wh, char* ws){
  const int md = *(const int*)(ws + OFF_MODE);
  const int j = blockIdx.x, k = threadIdx.x;
  ((u16*)(ws + OFF_WHP))[j*256 + k] = f2bf(ldv(Wh, k*768 + j, md));
}

// ---- GRU: 32 blocks = 8 groups x 4 slices; 512 thr / 8 waves ----
__launch_bounds__(512, 1)
__global__ void k_gru(const int* __restrict__ X, const void* __restrict__ brec,
                      char* __restrict__ ws, void* __restrict__ outv){
  const int tid = threadIdx.x;
  const int w   = tid >> 6, ln = tid & 63;
  const int l15 = ln & 15, l4 = ln >> 4;
  const int g = blockIdx.x >> 2, r = blockIdx.x & 3;

  const int md = *(const int*)(ws + OFF_MODE);
  const float* embw = (const float*)(ws + OFF_EMBW);
  const float* beff = (const float*)(ws + OFF_BEFF);
  const u16*   whp  = (const u16*)(ws + OFF_WHP);
  u32* hgp = (u32*)(ws + OFF_HGP);

  __shared__ int   Xs[16*512];           // 32 KB
  __shared__ float xwlds[2][16][196];    // 25 KB
  __shared__ float hwp[2][16][196];      // 25 KB
  __shared__ u16   hstage[2][16][272];   // 17 KB

  for (int i = tid; i < 2048; i += 512)
    ((i32x4*)Xs)[i] = ((const i32x4*)(X + g*16*512))[i];

  // persistent Wh B-frags: wave w -> subtile w&3, K-half w>>2
  const int qs = (w >> 2) * 4;
  s16x8 Bf[3][4];
  #pragma unroll
  for (int gg=0; gg<3; ++gg){
    const int col = gg*256 + r*64 + (w&3)*16 + l15;
    #pragma unroll
    for (int qi=0; qi<4; ++qi)
      Bf[gg][qi] = *(const s16x8*)(whp + col*256 + (qs+qi)*32 + l4*8);
  }

  // gates: thread -> h-col hc = r*64+(tid&63), rows tr, tr+8
  const int c63 = tid & 63;
  const int tr  = (tid >> 6) & 7;
  const int hc  = r*64 + c63;
  const float br0 = ldv(brec,       hc, md);
  const float br1 = ldv(brec, 256 + hc, md);
  const float br2 = ldv(brec, 512 + hc, md);

  // gather: chunk ids cid1 = tid, cid2 = tid+512 (tid<256 only)
  const int row1 = tid / 48,      rem1 = tid % 48;
  const int gg1  = rem1 / 16,     cc1  = rem1 % 16;
  const int cid2 = tid + 512;
  const int row2 = cid2 / 48,     rem2 = cid2 % 48;
  const int gg2  = rem2 / 16,     cc2  = rem2 % 16;
  const bool two = (tid < 256);
  const int gcol1 = gg1*256 + r*64 + cc1*4;
  const int gcol2 = gg2*256 + r*64 + cc2*4;
  const f32x4 be1 = *(const f32x4*)(beff + gcol1);
  const f32x4 be2 = *(const f32x4*)(beff + gcol2);

  // h-stage: thread -> row srow, 8 packed cols at sc0
  const int srow = tid >> 5, sc0 = (tid & 31) * 8;

  __syncthreads();   // Xs staged

  // prologue: xw(0) -> xwlds[0]
  {
    f32x4 v1 = be1, v2 = be2;
    #pragma unroll
    for (int d=0; d<5; ++d){
      const int t = d - 2;
      if ((unsigned)t < 512u){
        const int ch1 = Xs[row1*512 + t] & 127;
        v1 += *(const f32x4*)(embw + (size_t)(d*128 + ch1)*768 + gcol1);
        if (two){
          const int ch2 = Xs[row2*512 + t] & 127;
          v2 += *(const f32x4*)(embw + (size_t)(d*128 + ch2)*768 + gcol2);
        }
      }
    }
    *(f32x4*)&xwlds[0][row1][gg1*64 + cc1*4] = v1;
    if (two) *(f32x4*)&xwlds[0][row2][gg2*64 + cc2*4] = v2;
  }
  float hpA = 0.f, hpB = 0.f;
  __syncthreads();

  for (int s = 0; s < 512; ++s){
    const int par = s & 1;

    // S1) spin-load h(s): data itself carries step-mark in bit0 of each u32.
    //     expected mark em = (s>>1)&1 (regions recycle every 2 steps).
    const u32 em = (u32)((s >> 1) & 1);
    const u32* hb = hgp + (unsigned)par*32768u + (unsigned)g*4096u
                    + (unsigned)srow*256u + (unsigned)sc0;
    u64 d0, d1, d2, d3;
    {
      int guard = 0;
      for (;;){
        d0 = __hip_atomic_load((const u64*)hb+0, __ATOMIC_RELAXED, __HIP_MEMORY_SCOPE_AGENT);
        d1 = __hip_atomic_load((const u64*)hb+1, __ATOMIC_RELAXED, __HIP_MEMORY_SCOPE_AGENT);
        d2 = __hip_atomic_load((const u64*)hb+2, __ATOMIC_RELAXED, __HIP_MEMORY_SCOPE_AGENT);
        d3 = __hip_atomic_load((const u64*)hb+3, __ATOMIC_RELAXED, __HIP_MEMORY_SCOPE_AGENT);
        const u64 ba = d0 & d1 & d2 & d3;
        const u64 bo = d0 | d1 | d2 | d3;
        const bool ok = em ? ((((ba >> 32) & ba) & 1ull) == 1ull)
                           : ((((bo >> 32) | bo) & 1ull) == 0ull);
        if (ok || ++guard > (1<<22)) break;   // guard: fail visibly, no hang
      }
    }
    // de-interleave word = (hi<<16) | lo  -> stage planes
    {
      u32 wd[8] = {(u32)d0,(u32)(d0>>32),(u32)d1,(u32)(d1>>32),
                   (u32)d2,(u32)(d2>>32),(u32)d3,(u32)(d3>>32)};
      s16x8 hi, lo;
      #pragma unroll
      for (int j=0; j<8; ++j){ hi[j] = (short)(wd[j] >> 16); lo[j] = (short)(wd[j] & 0xFFFFu); }
      *(s16x8*)&hstage[0][srow][sc0] = hi;
      *(s16x8*)&hstage[1][srow][sc0] = lo;
    }
    __syncthreads();                          // barA: stage ready

    // S2) partial hw over this wave's K-half: 24 MFMAs
    f32x4 a0 = {0.f,0.f,0.f,0.f}, a1 = a0, a2 = a0;
    #pragma unroll
    for (int qi=0; qi<4; ++qi){
      const int kb = (qs+qi)*32 + l4*8;
      const s16x8 ahi = *(const s16x8*)&hstage[0][l15][kb];
      const s16x8 alo = *(const s16x8*)&hstage[1][l15][kb];
      a0 = __builtin_amdgcn_mfma_f32_16x16x32_bf16(ahi, Bf[0][qi], a0, 0,0,0);
      a1 = __builtin_amdgcn_mfma_f32_16x16x32_bf16(ahi, Bf[1][qi], a1, 0,0,0);
      a2 = __builtin_amdgcn_mfma_f32_16x16x32_bf16(ahi, Bf[2][qi], a2, 0,0,0);
      a0 = __builtin_amdgcn_mfma_f32_16x16x32_bf16(alo, Bf[0][qi], a0, 0,0,0);
      a1 = __builtin_amdgcn_mfma_f32_16x16x32_bf16(alo, Bf[1][qi], a1, 0,0,0);
      a2 = __builtin_amdgcn_mfma_f32_16x16x32_bf16(alo, Bf[2][qi], a2, 0,0,0);
    }
    {
      const int kh = w >> 2, sc = (w&3)*16 + l15;
      #pragma unroll
      for (int p=0; p<4; ++p){
        hwp[kh][l4*4+p][       sc] = a0[p];
        hwp[kh][l4*4+p][ 64 + sc] = a1[p];
        hwp[kh][l4*4+p][128 + sc] = a2[p];
      }
    }

    // S3) gather xw(s+1): issue now (L2 latency hides until gates consume)
    f32x4 n1, n2;
    if (s < 511){
      n1 = be1; n2 = be2;
      #pragma unroll
      for (int d=0; d<5; ++d){
        const int t = s - 1 + d;
        if ((unsigned)t < 512u){
          const int ch1 = Xs[row1*512 + t] & 127;
          n1 += *(const f32x4*)(embw + (size_t)(d*128 + ch1)*768 + gcol1);
          if (two){
            const int ch2 = Xs[row2*512 + t] & 127;
            n2 += *(const f32x4*)(embw + (size_t)(d*128 + ch2)*768 + gcol2);
          }
        }
      }
    }
    __syncthreads();                          // barB: hwp ready

    // S4) gates for units (tr, hc) and (tr+8, hc)
    float hnA, hnB;
    #pragma unroll
    for (int u=0; u<2; ++u){
      const int row = tr + u*8;
      const float hz = hwp[0][row][      c63] + hwp[1][row][      c63] + br0;
      const float hr = hwp[0][row][ 64 + c63] + hwp[1][row][ 64 + c63] + br1;
      const float hh = hwp[0][row][128 + c63] + hwp[1][row][128 + c63] + br2;
      const float xz = xwlds[par][row][      c63];
      const float xr = xwlds[par][row][ 64 + c63];
      const float xh = xwlds[par][row][128 + c63];
      const float hp = u ? hpB : hpA;
      const float z  = 1.f/(1.f + __expf(-(xz + hz)));
      const float rg = 1.f/(1.f + __expf(-(xr + hr)));
      const float pre = xh + rg*hh;
      const float e2  = __expf(-2.f*fabsf(pre));
      const float th  = __builtin_copysignf((1.f - e2)/(1.f + e2), pre);
      const float hn  = z*hp + (1.f - z)*th;
      if (u) hnB = hn; else hnA = hn;
    }
    hpA = hnA; hpB = hnB;

    // S5) publish h(s+1) with embedded mark, or final output
    if (s == 511){
      const int i0 = (g*16 + tr)*256 + hc;
      if (md){ ((float*)outv)[i0] = hnA; ((float*)outv)[i0 + 8*256] = hnB; }
      else   { ((u16*)outv)[i0] = f2bf(hnA); ((u16*)outv)[i0 + 8*256] = f2bf(hnB); }
    } else {
      const u32 sm = (u32)(((s + 1) >> 1) & 1);
      u32* hb2 = hgp + (unsigned)(par^1)*32768u + (unsigned)g*4096u;
      #pragma unroll
      for (int u=0; u<2; ++u){
        const float hn = u ? hnB : hnA;
        const u32 bh = f2bf(hn);
        u32 bl = f2bf(hn - bf2f((u16)bh));
        bl = (bl & ~1u) | sm;                 // steal lo LSB for the step-mark
        __hip_atomic_store(hb2 + (tr + u*8)*256 + hc, (bh << 16) | bl,
                           __ATOMIC_RELAXED, __HIP_MEMORY_SCOPE_AGENT);
      }
      // xw(s+1) -> other LDS buffer
      *(f32x4*)&xwlds[par^1][row1][gg1*64 + cc1*4] = n1;
      if (two) *(f32x4*)&xwlds[par^1][row2][gg2*64 + cc2*4] = n2;
    }
    // no end-of-step barrier needed: barA(s+1) orders hstage WAR; stores are
    // self-validating (no drain/flag).
  }
}

extern "C" void kernel_launch(void* const* d_in, const int* in_sizes, int n_in,
                              void* d_out, int out_size, void* d_ws, size_t ws_size,
                              hipStream_t stream){
  const int* X = (const int*)d_in[0];
  char* ws = (char*)d_ws;
  if (ws_size < WS_NEED) return;

  k_init <<<256, 256, 0, stream>>>(ws);
  k_probe<<<  1,  64, 0, stream>>>(d_in[1], ws);
  k_wc   <<<320, 256, 0, stream>>>(d_in[2], d_in[4], d_in[6], d_in[8], d_in[10], ws);
  k_beff <<<  3, 256, 0, stream>>>(d_in[3], d_in[5], d_in[7], d_in[9], d_in[10], d_in[12], ws);
  k_embw <<<640, 256, 0, stream>>>(d_in[1], ws);
  k_whp  <<<768, 256, 0, stream>>>(d_in[11], ws);
  k_gru  <<< 32, 512, 0, stream>>>(X, d_in[13], ws, d_out);
}

// Round 14
// 2009.811 us; speedup vs baseline: 2.8452x; 1.0632x over previous
//
#include <hip/hip_runtime.h>
#include <hip/hip_bf16.h>

// ---------------------------------------------------------------------------
// CharRNN: emb -> 4x conv1d(SAME) -> concat -> GRU(256) last state.
//
// xw[b,t,:] = beff + sum_{d=0..4} EmbW[d][X[b,t+d-2]][:]   (f32 tables in ws)
//
// R14: R13 (1-barrier, per-lane spin) timed out; R12 (XCD-local) failed.
// Revert to R11 VERBATIM (passed, k_gru 1975us) with exactly ONE change:
// the S1 spin probe's 4 serialized u64 agent atomic loads are replaced by
// TWO batched global_load_dwordx4 (sc0 sc1) + ONE s_waitcnt that takes the
// loaded tuples as "+v" operands -> consumers SSA-depend on the waitcnt asm
// (rule-#18-proof). One ~900cy round trip per probe instead of up to 4.
// Everything else (marks, barA staging, barB, gates, publisher atomics,
// precompute) is byte-identical to R11.
// ---------------------------------------------------------------------------

typedef float f32x4 __attribute__((ext_vector_type(4)));
typedef short s16x8 __attribute__((ext_vector_type(8)));
typedef int   i32x4 __attribute__((ext_vector_type(4)));
typedef unsigned short u16;
typedef unsigned int   u32;
typedef unsigned long long u64;

// ws byte offsets
#define OFF_WC    0u         // f32  [5][64][768]
#define OFF_EMBW  983040u    // f32  [5][128][768]
#define OFF_BEFF  2949120u   // f32  [768]
#define OFF_WHP   2952192u   // bf16 [768][256] (Wh^T)
#define OFF_MODE  3345408u   // int
#define OFF_HGP   3345472u   // u32 [2][8][16][256]  (par, group, row, hcol)
#define WS_NEED   3607616u

__device__ __forceinline__ float bf2f(u16 v){
  unsigned u = ((unsigned)v) << 16; return __builtin_bit_cast(float, u);
}
__device__ __forceinline__ u16 f2bf(float f){
  unsigned u = __builtin_bit_cast(unsigned, f);
  unsigned r = u + 0x7FFFu + ((u >> 16) & 1u);
  return (u16)(r >> 16);
}
__device__ __forceinline__ float ldv(const void* p, int i, int m){
  return m ? ((const float*)p)[i] : bf2f(((const u16*)p)[i]);
}

// ---- init: zero both h parity planes (mark bits 0 -> steps 0,1 validate) ----
__global__ void k_init(char* ws){
  int idx = blockIdx.x*256 + threadIdx.x;
  u32* hg = (u32*)(ws + OFF_HGP);
  if (idx < 65536) hg[idx] = 0u;
}

// ---- probe: detect storage dtype of emb_table ----
__global__ void k_probe(const void* __restrict__ emb, char* ws){
  const u16* w = (const u16*)emb;
  const int ln = threadIdx.x;
  bool bad = false;
  for (int j = 0; j < 8; ++j){
    u16 v = w[ln*8 + j];
    if (((v >> 7) & 0xFF) >= 0x86) bad = true;
  }
  unsigned long long m = __ballot(bad);
  if (ln == 0) *(int*)(ws + OFF_MODE) = (__popcll(m) > 4) ? 1 : 0;
}

// ---- Wc[d][e][j] = sum_br sum_c w_br[d-2+pad][e][c] * Wx[off_br+c][j] ----
__global__ void k_wc(const void* __restrict__ w2, const void* __restrict__ w3,
                     const void* __restrict__ w4, const void* __restrict__ w5,
                     const void* __restrict__ Wx, char* ws){
  const int md = *(const int*)(ws + OFF_MODE);
  const int d = blockIdx.x >> 6;
  const int e = blockIdx.x & 63;
  const int j0 = threadIdx.x;
  const void* wv[4] = {w2,w3,w4,w5};
  const int Kk[4] = {2,3,4,5}, pd[4] = {0,1,1,2};
  float a0=0.f, a1=0.f, a2=0.f;
  for (int br=0; br<4; ++br){
    int k = d - 2 + pd[br];
    if (k < 0 || k >= Kk[br]) continue;
    const int wbase  = (k*64 + e)*128;
    const int wxbase = (br*128)*768;
    for (int c=0; c<128; ++c){
      float wcv = ldv(wv[br], wbase + c, md);
      a0 += wcv * ldv(Wx, wxbase + c*768 + j0      , md);
      a1 += wcv * ldv(Wx, wxbase + c*768 + j0 + 256, md);
      a2 += wcv * ldv(Wx, wxbase + c*768 + j0 + 512, md);
    }
  }
  float* o = (float*)(ws + OFF_WC) + (d*64 + e)*768;
  o[j0] = a0; o[j0+256] = a1; o[j0+512] = a2;
}

// ---- beff[j] = b_in[j] + sum_br sum_c b_br[c]*Wx[off+c][j] ----
__global__ void k_beff(const void* __restrict__ b2, const void* __restrict__ b3,
                       const void* __restrict__ b4, const void* __restrict__ b5,
                       const void* __restrict__ Wx, const void* __restrict__ bin,
                       char* ws){
  const int md = *(const int*)(ws + OFF_MODE);
  int j = blockIdx.x*256 + threadIdx.x;
  if (j >= 768) return;
  const void* bv[4] = {b2,b3,b4,b5};
  float acc = ldv(bin, j, md);
  for (int br=0; br<4; ++br)
    for (int c=0; c<128; ++c)
      acc += ldv(bv[br], c, md) * ldv(Wx, (br*128 + c)*768 + j, md);
  ((float*)(ws + OFF_BEFF))[j] = acc;
}

// ---- EmbW[d][ch][j] = sum_e emb[ch][e] * Wc[d][e][j]  (f32 out) ----
__global__ void k_embw(const void* __restrict__ emb, char* ws){
  const int md = *(const int*)(ws + OFF_MODE);
  const int d = blockIdx.x >> 7, ch = blockIdx.x & 127;
  const float* wc = (const float*)(ws + OFF_WC) + d*64*768;
  float* ew = (float*)(ws + OFF_EMBW) + (size_t)(d*128 + ch)*768;
  const int j0 = threadIdx.x;
  float a0=0.f, a1=0.f, a2=0.f;
  for (int e=0; e<64; ++e){
    float ev = ldv(emb, ch*64 + e, md);
    a0 += ev*wc[e*768 + j0      ];
    a1 += ev*wc[e*768 + j0 + 256];
    a2 += ev*wc[e*768 + j0 + 512];
  }
  ew[j0] = a0; ew[j0+256] = a1; ew[j0+512] = a2;
}

// ---- whp[j][k] = Wh[k][j]  (bf16 out) ----
__global__ void k_whp(const void* __restrict__ Wh, char* ws){
  const int md = *(const int*)(ws + OFF_MODE);
  const int j = blockIdx.x, k = threadIdx.x;
  ((u16*)(ws + OFF_WHP))[j*256 + k] = f2bf(ldv(Wh, k*768 + j, md));
}

// ---- GRU: 32 blocks = 8 groups x 4 slices; 512 thr / 8 waves ----
__launch_bounds__(512, 1)
__global__ void k_gru(const int* __restrict__ X, const void* __restrict__ brec,
                      char* __restrict__ ws, void* __restrict__ outv){
  const int tid = threadIdx.x;
  const int w   = tid >> 6, ln = tid & 63;
  const int l15 = ln & 15, l4 = ln >> 4;
  const int g = blockIdx.x >> 2, r = blockIdx.x & 3;

  const int md = *(const int*)(ws + OFF_MODE);
  const float* embw = (const float*)(ws + OFF_EMBW);
  const float* beff = (const float*)(ws + OFF_BEFF);
  const u16*   whp  = (const u16*)(ws + OFF_WHP);
  u32* hgp = (u32*)(ws + OFF_HGP);

  __shared__ int   Xs[16*512];           // 32 KB
  __shared__ float xwlds[2][16][196];    // 25 KB
  __shared__ float hwp[2][16][196];      // 25 KB
  __shared__ u16   hstage[2][16][272];   // 17 KB

  for (int i = tid; i < 2048; i += 512)
    ((i32x4*)Xs)[i] = ((const i32x4*)(X + g*16*512))[i];

  // persistent Wh B-frags: wave w -> subtile w&3, K-half w>>2
  const int qs = (w >> 2) * 4;
  s16x8 Bf[3][4];
  #pragma unroll
  for (int gg=0; gg<3; ++gg){
    const int col = gg*256 + r*64 + (w&3)*16 + l15;
    #pragma unroll
    for (int qi=0; qi<4; ++qi)
      Bf[gg][qi] = *(const s16x8*)(whp + col*256 + (qs+qi)*32 + l4*8);
  }

  // gates: thread -> h-col hc = r*64+(tid&63), rows tr, tr+8
  const int c63 = tid & 63;
  const int tr  = (tid >> 6) & 7;
  const int hc  = r*64 + c63;
  const float br0 = ldv(brec,       hc, md);
  const float br1 = ldv(brec, 256 + hc, md);
  const float br2 = ldv(brec, 512 + hc, md);

  // gather: chunk ids cid1 = tid, cid2 = tid+512 (tid<256 only)
  const int row1 = tid / 48,      rem1 = tid % 48;
  const int gg1  = rem1 / 16,     cc1  = rem1 % 16;
  const int cid2 = tid + 512;
  const int row2 = cid2 / 48,     rem2 = cid2 % 48;
  const int gg2  = rem2 / 16,     cc2  = rem2 % 16;
  const bool two = (tid < 256);
  const int gcol1 = gg1*256 + r*64 + cc1*4;
  const int gcol2 = gg2*256 + r*64 + cc2*4;
  const f32x4 be1 = *(const f32x4*)(beff + gcol1);
  const f32x4 be2 = *(const f32x4*)(beff + gcol2);

  // h-stage: thread -> row srow, 8 packed cols at sc0_
  const int srow = tid >> 5, sc0_ = (tid & 31) * 8;

  __syncthreads();   // Xs staged

  // prologue: xw(0) -> xwlds[0]
  {
    f32x4 v1 = be1, v2 = be2;
    #pragma unroll
    for (int d=0; d<5; ++d){
      const int t = d - 2;
      if ((unsigned)t < 512u){
        const int ch1 = Xs[row1*512 + t] & 127;
        v1 += *(const f32x4*)(embw + (size_t)(d*128 + ch1)*768 + gcol1);
        if (two){
          const int ch2 = Xs[row2*512 + t] & 127;
          v2 += *(const f32x4*)(embw + (size_t)(d*128 + ch2)*768 + gcol2);
        }
      }
    }
    *(f32x4*)&xwlds[0][row1][gg1*64 + cc1*4] = v1;
    if (two) *(f32x4*)&xwlds[0][row2][gg2*64 + cc2*4] = v2;
  }
  float hpA = 0.f, hpB = 0.f;
  __syncthreads();

  for (int s = 0; s < 512; ++s){
    const int par = s & 1;

    // S1) spin until this thread's 8 h-words are valid. Batched probe:
    //     2x global_load_dwordx4 (sc0 sc1) + ONE waitcnt carrying the
    //     tuples as "+v" -> consumers SSA-depend on the waitcnt asm.
    const u32 em = (u32)((s >> 1) & 1);
    const u32* hb = hgp + (unsigned)par*32768u + (unsigned)g*4096u
                    + (unsigned)srow*256u + (unsigned)sc0_;
    i32x4 A, B;
    {
      int guard = 0;
      for (;;){
        asm volatile("global_load_dwordx4 %0, %2, off sc0 sc1\n\t"
                     "global_load_dwordx4 %1, %3, off sc0 sc1"
                     : "=&v"(A), "=&v"(B)
                     : "v"(hb), "v"(hb + 4)
                     : "memory");
        asm volatile("s_waitcnt vmcnt(0)" : "+v"(A), "+v"(B) :: "memory");
        __builtin_amdgcn_sched_barrier(0);
        const u32 ba = (u32)A[0] & (u32)A[1] & (u32)A[2] & (u32)A[3]
                     & (u32)B[0] & (u32)B[1] & (u32)B[2] & (u32)B[3];
        const u32 bo = (u32)A[0] | (u32)A[1] | (u32)A[2] | (u32)A[3]
                     | (u32)B[0] | (u32)B[1] | (u32)B[2] | (u32)B[3];
        const bool ok = em ? ((ba & 1u) == 1u) : ((bo & 1u) == 0u);
        if (ok || ++guard > (1<<20)) break;   // guard: fail visibly, no hang
      }
    }
    // de-interleave word = (hi<<16) | lo  -> stage planes
    {
      u32 wd[8] = {(u32)A[0],(u32)A[1],(u32)A[2],(u32)A[3],
                   (u32)B[0],(u32)B[1],(u32)B[2],(u32)B[3]};
      s16x8 hi, lo;
      #pragma unroll
      for (int j=0; j<8; ++j){ hi[j] = (short)(wd[j] >> 16); lo[j] = (short)(wd[j] & 0xFFFFu); }
      *(s16x8*)&hstage[0][srow][sc0_] = hi;
      *(s16x8*)&hstage[1][srow][sc0_] = lo;
    }
    __syncthreads();                          // barA: stage ready

    // S2) partial hw over this wave's K-half: 24 MFMAs
    f32x4 a0 = {0.f,0.f,0.f,0.f}, a1 = a0, a2 = a0;
    #pragma unroll
    for (int qi=0; qi<4; ++qi){
      const int kb = (qs+qi)*32 + l4*8;
      const s16x8 ahi = *(const s16x8*)&hstage[0][l15][kb];
      const s16x8 alo = *(const s16x8*)&hstage[1][l15][kb];
      a0 = __builtin_amdgcn_mfma_f32_16x16x32_bf16(ahi, Bf[0][qi], a0, 0,0,0);
      a1 = __builtin_amdgcn_mfma_f32_16x16x32_bf16(ahi, Bf[1][qi], a1, 0,0,0);
      a2 = __builtin_amdgcn_mfma_f32_16x16x32_bf16(ahi, Bf[2][qi], a2, 0,0,0);
      a0 = __builtin_amdgcn_mfma_f32_16x16x32_bf16(alo, Bf[0][qi], a0, 0,0,0);
      a1 = __builtin_amdgcn_mfma_f32_16x16x32_bf16(alo, Bf[1][qi], a1, 0,0,0);
      a2 = __builtin_amdgcn_mfma_f32_16x16x32_bf16(alo, Bf[2][qi], a2, 0,0,0);
    }
    {
      const int kh = w >> 2, sc = (w&3)*16 + l15;
      #pragma unroll
      for (int p=0; p<4; ++p){
        hwp[kh][l4*4+p][       sc] = a0[p];
        hwp[kh][l4*4+p][ 64 + sc] = a1[p];
        hwp[kh][l4*4+p][128 + sc] = a2[p];
      }
    }

    // S3) gather xw(s+1): issue now (L2 latency hides until gates consume)
    f32x4 n1, n2;
    if (s < 511){
      n1 = be1; n2 = be2;
      #pragma unroll
      for (int d=0; d<5; ++d){
        const int t = s - 1 + d;
        if ((unsigned)t < 512u){
          const int ch1 = Xs[row1*512 + t] & 127;
          n1 += *(const f32x4*)(embw + (size_t)(d*128 + ch1)*768 + gcol1);
          if (two){
            const int ch2 = Xs[row2*512 + t] & 127;
            n2 += *(const f32x4*)(embw + (size_t)(d*128 + ch2)*768 + gcol2);
          }
        }
      }
    }
    __syncthreads();                          // barB: hwp ready

    // S4) gates for units (tr, hc) and (tr+8, hc)
    float hnA, hnB;
    #pragma unroll
    for (int u=0; u<2; ++u){
      const int row = tr + u*8;
      const float hz = hwp[0][row][      c63] + hwp[1][row][      c63] + br0;
      const float hr = hwp[0][row][ 64 + c63] + hwp[1][row][ 64 + c63] + br1;
      const float hh = hwp[0][row][128 + c63] + hwp[1][row][128 + c63] + br2;
      const float xz = xwlds[par][row][      c63];
      const float xr = xwlds[par][row][ 64 + c63];
      const float xh = xwlds[par][row][128 + c63];
      const float hp = u ? hpB : hpA;
      const float z  = 1.f/(1.f + __expf(-(xz + hz)));
      const float rg = 1.f/(1.f + __expf(-(xr + hr)));
      const float pre = xh + rg*hh;
      const float e2  = __expf(-2.f*fabsf(pre));
      const float th  = __builtin_copysignf((1.f - e2)/(1.f + e2), pre);
      const float hn  = z*hp + (1.f - z)*th;
      if (u) hnB = hn; else hnA = hn;
    }
    hpA = hnA; hpB = hnB;

    // S5) publish h(s+1) with embedded mark, or final output
    if (s == 511){
      const int i0 = (g*16 + tr)*256 + hc;
      if (md){ ((float*)outv)[i0] = hnA; ((float*)outv)[i0 + 8*256] = hnB; }
      else   { ((u16*)outv)[i0] = f2bf(hnA); ((u16*)outv)[i0 + 8*256] = f2bf(hnB); }
    } else {
      const u32 sm = (u32)(((s + 1) >> 1) & 1);
      u32* hb2 = hgp + (unsigned)(par^1)*32768u + (unsigned)g*4096u;
      #pragma unroll
      for (int u=0; u<2; ++u){
        const float hn = u ? hnB : hnA;
        const u32 bh = f2bf(hn);
        u32 bl = f2bf(hn - bf2f((u16)bh));
        bl = (bl & ~1u) | sm;                 // steal lo LSB for the step-mark
        __hip_atomic_store(hb2 + (tr + u*8)*256 + hc, (bh << 16) | bl,
                           __ATOMIC_RELAXED, __HIP_MEMORY_SCOPE_AGENT);
      }
      // xw(s+1) -> other LDS buffer
      *(f32x4*)&xwlds[par^1][row1][gg1*64 + cc1*4] = n1;
      if (two) *(f32x4*)&xwlds[par^1][row2][gg2*64 + cc2*4] = n2;
    }
  }
}

extern "C" void kernel_launch(void* const* d_in, const int* in_sizes, int n_in,
                              void* d_out, int out_size, void* d_ws, size_t ws_size,
                              hipStream_t stream){
  const int* X = (const int*)d_in[0];
  char* ws = (char*)d_ws;
  if (ws_size < WS_NEED) return;

  k_init <<<256, 256, 0, stream>>>(ws);
  k_probe<<<  1,  64, 0, stream>>>(d_in[1], ws);
  k_wc   <<<320, 256, 0, stream>>>(d_in[2], d_in[4], d_in[6], d_in[8], d_in[10], ws);
  k_beff <<<  3, 256, 0, stream>>>(d_in[3], d_in[5], d_in[7], d_in[9], d_in[10], d_in[12], ws);
  k_embw <<<640, 256, 0, stream>>>(d_in[1], ws);
  k_whp  <<<768, 256, 0, stream>>>(d_in[11], ws);
  k_gru  <<< 32, 512, 0, stream>>>(X, d_in[13], ws, d_out);
}